// Round 13
// baseline (63.342 us; speedup 1.0000x reference)
//
#include <hip/hip_runtime.h>

#define M_DIM 64
#define K_DIM 8192
#define N_DIM 8192
#define QB 32
#define NT 128              // cols per block (32 per wave for MFMA)
#define KC 64               // K per stage (2 quant blocks)
#define SPLITS 8
#define KSPLIT (K_DIM / SPLITS)    // 1024
#define NSTAGE (KSPLIT / KC)       // 16

typedef __attribute__((ext_vector_type(8))) short short8;     // MFMA A/B frag
typedef __attribute__((ext_vector_type(8))) unsigned short ushort8;
typedef __attribute__((ext_vector_type(4))) float f32x4;

static_assert(NSTAGE * KC == KSPLIT, "split must tile");

// f32 -> bf16 round-to-nearest-even
__device__ __forceinline__ unsigned short f2bf(float f) {
    unsigned u = __builtin_bit_cast(unsigned, f);
    u += 0x7fffu + ((u >> 16) & 1u);
    return (unsigned short)(u >> 16);
}

// Fallback path only: clears poison with bias; qgemm<false> atomicAdds on top.
__global__ __launch_bounds__(256) void bias_init(const float* __restrict__ bias,
                                                 float* __restrict__ out) {
    int i = (blockIdx.x * 256 + threadIdx.x) * 4;
    *(f32x4*)(out + i) = *(const f32x4*)(bias + (i & (N_DIM - 1)));
}

// R13: DRAM-granule probe. Identical recipe to the 59.4us champion except
// each lane owns TWO adjacent weight columns and loads int2 (dwordx2):
// one wave-instruction = 64 lanes x 8B = 512B contiguous (2x the champion's
// 256B), halving HBM page-visits per byte. All validated pieces unchanged:
// [col][k] LDS tiles at 72-short stride, x LDS staging, one __syncthreads
// per stage, 1-deep prefetch, partial-store epilogue.
template <bool PART>
__global__ __launch_bounds__(256, 2) void qgemm(
    const float* __restrict__ x,       // [M][K]
    const float* __restrict__ scales,  // [K/QB][N]
    const float* __restrict__ zeros,   // [K/QB][N]
    const int*   __restrict__ qw,      // [K][N], values 0..255
    float*       __restrict__ outp)    // PART ? [SPLITS][M][N] : [M][N]
{
    __shared__ unsigned short lq[2][NT][72];     // [col][k] bf16, 144B rows
    __shared__ unsigned short lx[2][M_DIM][72];  // [m][k] bf16

    const int tid  = threadIdx.x;
    const int lane = tid & 63;
    const int w    = tid >> 6;          // wave 0..3
    const int q    = lane >> 4;         // k-slot / C row-quarter
    const int lm   = lane & 15;

    const int n0 = blockIdx.x * NT;
    const int k0 = blockIdx.y * KSPLIT;

    const int cp   = n0 + 2 * lane;     // this lane's column PAIR
    const int xrow = tid >> 2;          // x staging: row 0..63
    const int xcol = (tid & 3) * 16;    // 16 k's per thread

    // stage registers
    int2   qv[16];                      // rows 16s+4w+j (s,j in 0..3) x 2 cols
    float2 sv[2], zv[2];                // per quant-block, per col
    f32x4  xv[4];

    auto load_stage = [&](int kk) {
        #pragma unroll
        for (int s = 0; s < 4; ++s)
            #pragma unroll
            for (int j = 0; j < 4; ++j)
                qv[4 * s + j] = *(const int2*)(qw +
                    (size_t)(kk + 16 * s + 4 * w + j) * N_DIM + cp);
        const int b0 = kk >> 5;
        sv[0] = *(const float2*)(scales + (size_t)b0 * N_DIM + cp);
        sv[1] = *(const float2*)(scales + (size_t)(b0 + 1) * N_DIM + cp);
        zv[0] = *(const float2*)(zeros  + (size_t)b0 * N_DIM + cp);
        zv[1] = *(const float2*)(zeros  + (size_t)(b0 + 1) * N_DIM + cp);
        #pragma unroll
        for (int i = 0; i < 4; ++i)
            xv[i] = *(const f32x4*)(x + (size_t)xrow * K_DIM + kk + xcol + 4 * i);
    };

    load_stage(k0);

    f32x4 acc[2][4];                    // [colfrag g][rowfrag r]
    #pragma unroll
    for (int g = 0; g < 2; ++g)
        #pragma unroll
        for (int r = 0; r < 4; ++r) acc[g][r] = (f32x4){0.f, 0.f, 0.f, 0.f};

    for (int t = 0; t < NSTAGE; ++t) {
        const int cur = t & 1;

        // --- dequant stage-t regs -> packed bf16, both cols ---
        const float2 nz0 = {-sv[0].x * zv[0].x, -sv[0].y * zv[0].y};
        const float2 nz1 = {-sv[1].x * zv[1].x, -sv[1].y * zv[1].y};
        const float2 s0r = sv[0], s1r = sv[1];
        uint2 qd0[4], qd1[4];           // per s: col cp (qd0), col cp+1 (qd1)
        #pragma unroll
        for (int s = 0; s < 4; ++s) {
            const float2 sc = (s < 2) ? s0r : s1r;
            const float2 nz = (s < 2) ? nz0 : nz1;
            unsigned short a0 = f2bf(fmaf((float)qv[4 * s + 0].x, sc.x, nz.x));
            unsigned short a1 = f2bf(fmaf((float)qv[4 * s + 1].x, sc.x, nz.x));
            unsigned short a2 = f2bf(fmaf((float)qv[4 * s + 2].x, sc.x, nz.x));
            unsigned short a3 = f2bf(fmaf((float)qv[4 * s + 3].x, sc.x, nz.x));
            unsigned short b0 = f2bf(fmaf((float)qv[4 * s + 0].y, sc.y, nz.y));
            unsigned short b1 = f2bf(fmaf((float)qv[4 * s + 1].y, sc.y, nz.y));
            unsigned short b2 = f2bf(fmaf((float)qv[4 * s + 2].y, sc.y, nz.y));
            unsigned short b3 = f2bf(fmaf((float)qv[4 * s + 3].y, sc.y, nz.y));
            qd0[s].x = (unsigned)a0 | ((unsigned)a1 << 16);
            qd0[s].y = (unsigned)a2 | ((unsigned)a3 << 16);
            qd1[s].x = (unsigned)b0 | ((unsigned)b1 << 16);
            qd1[s].y = (unsigned)b2 | ((unsigned)b3 << 16);
        }
        ushort8 xw0, xw1;
        #pragma unroll
        for (int e = 0; e < 4; ++e) {
            xw0[e]     = f2bf(xv[0][e]);
            xw0[4 + e] = f2bf(xv[1][e]);
            xw1[e]     = f2bf(xv[2][e]);
            xw1[4 + e] = f2bf(xv[3][e]);
        }

        // --- prefetch stage t+1 (in flight across the barrier) ---
        if (t + 1 < NSTAGE) load_stage(k0 + (t + 1) * KC);

        // --- stage to LDS (transposed [col][k], champion layout x2 cols) ---
        #pragma unroll
        for (int s = 0; s < 4; ++s) {
            *(uint2*)&lq[cur][2 * lane][16 * s + 4 * w]     = qd0[s];
            *(uint2*)&lq[cur][2 * lane + 1][16 * s + 4 * w] = qd1[s];
        }
        *(ushort8*)&lx[cur][xrow][xcol]     = xw0;
        *(ushort8*)&lx[cur][xrow][xcol + 8] = xw1;

        __syncthreads();

        // --- MFMA: wave w = cols [32w, 32w+32), 2 col-frags x 4 row-frags ---
        #pragma unroll
        for (int c = 0; c < 2; ++c) {
            short8 bf[2];
            #pragma unroll
            for (int g = 0; g < 2; ++g)
                bf[g] = *(const short8*)&lq[cur][32 * w + 16 * g + lm][32 * c + 8 * q];
            #pragma unroll
            for (int r = 0; r < 4; ++r) {
                const short8 af = *(const short8*)&lx[cur][16 * r + lm][32 * c + 8 * q];
                #pragma unroll
                for (int g = 0; g < 2; ++g)
                    acc[g][r] = __builtin_amdgcn_mfma_f32_16x16x32_bf16(
                        af, bf[g], acc[g][r], 0, 0, 0);
            }
        }
    }

    // epilogue: C layout col=lane&15, row=4*(lane>>4)+e (validated)
    #pragma unroll
    for (int g = 0; g < 2; ++g) {
        const int cn = n0 + 32 * w + 16 * g + lm;
        if (PART) {
            float* po = outp + (size_t)blockIdx.y * (M_DIM * (size_t)N_DIM);
            #pragma unroll
            for (int r = 0; r < 4; ++r) {
                const int m = 16 * r + 4 * q;
                #pragma unroll
                for (int e = 0; e < 4; ++e)
                    po[(size_t)(m + e) * N_DIM + cn] = acc[g][r][e];
            }
        } else {
            #pragma unroll
            for (int r = 0; r < 4; ++r) {
                const int m = 16 * r + 4 * q;
                #pragma unroll
                for (int e = 0; e < 4; ++e)
                    atomicAdd(outp + (size_t)(m + e) * N_DIM + cn, acc[g][r][e]);
            }
        }
    }
}

// out = bias + sum of SPLITS partials. Fully overwrites d_out every call.
__global__ __launch_bounds__(256) void reduce_bias(const float* __restrict__ part,
                                                   const float* __restrict__ bias,
                                                   float* __restrict__ out) {
    int i = (blockIdx.x * 256 + threadIdx.x) * 4;
    f32x4 s = *(const f32x4*)(bias + (i & (N_DIM - 1)));
    #pragma unroll
    for (int sp = 0; sp < SPLITS; ++sp)
        s += *(const f32x4*)(part + (size_t)sp * (M_DIM * (size_t)N_DIM) + i);
    *(f32x4*)(out + i) = s;
}

extern "C" void kernel_launch(void* const* d_in, const int* in_sizes, int n_in,
                              void* d_out, int out_size, void* d_ws, size_t ws_size,
                              hipStream_t stream) {
    const float* x      = (const float*)d_in[0];
    const float* scales = (const float*)d_in[1];
    const float* zeros  = (const float*)d_in[2];
    const float* bias   = (const float*)d_in[3];
    const int*   qw     = (const int*)d_in[4];
    float* out  = (float*)d_out;
    float* part = (float*)d_ws;

    const size_t need = (size_t)SPLITS * M_DIM * N_DIM * sizeof(float);  // 16 MB

    if (ws_size >= need) {
        qgemm<true><<<dim3(N_DIM / NT, SPLITS), 256, 0, stream>>>(
            x, scales, zeros, qw, part);
        reduce_bias<<<dim3((M_DIM * N_DIM) / 1024), 256, 0, stream>>>(part, bias, out);
    } else {
        bias_init<<<dim3((M_DIM * N_DIM) / 1024), 256, 0, stream>>>(bias, out);
        qgemm<false><<<dim3(N_DIM / NT, SPLITS), 256, 0, stream>>>(
            x, scales, zeros, qw, out);
    }
}